// Round 6
// baseline (234.293 us; speedup 1.0000x reference)
//
#include <hip/hip_runtime.h>
#include <hip/hip_fp16.h>

// Problem constants (fixed by setup_inputs / GTLModuleV1)
#define BATCH 4
#define CHAN  144
#define NPTS  16384
#define KNN   16
#define GRP   9
#define DIM   16
#define ROWU  (GRP * DIM)        // 144 uint32 per point = 576 B row
#define PCHUNK 32                // chunks per (b,g) pair -> 36*32 = 1152 blocks
#define NPAIR (BATCH * GRP)      // 36

#define TT 32

typedef __attribute__((ext_vector_type(2))) _Float16 h2v;
typedef __attribute__((ext_vector_type(4))) float f4v;   // clang vector: nt ops OK
typedef __attribute__((ext_vector_type(4))) int   i4v;   // clang vector: nt ops OK
__device__ __forceinline__ h2v as_h2(unsigned int u) {
  union { unsigned int u; h2v h; } c; c.u = u; return c.h;
}

// DPP helpers: quad_perm ops are VALU (no LDS pipe, ~4cy vs ~40cy bpermute).
template<int J>  // broadcast quad-lane J to all 4 lanes of the quad
__device__ __forceinline__ int ibcast(int v) {
  return __builtin_amdgcn_update_dpp(0, v, (J) * 0x55, 0xF, 0xF, true);
}
template<int C>  // C=0xB1: xor1 swap; C=0x4E: xor2 swap (within quad)
__device__ __forceinline__ float fxor(float x) {
  int r = __builtin_amdgcn_update_dpp(0, __builtin_bit_cast(int, x), C, 0xF, 0xF, true);
  return __builtin_bit_cast(float, r);
}

// (C,N) fp32 q,v -> (N, 144 uints): per group g, uint 2i = h2(k_{2i},k_{2i+1}),
// uint 2i+1 = h2(v_{2i},v_{2i+1}). Each (g,m) slice = 64 B; a uint4 at uint
// offset 16g+4d = dims 4d..4d+3 of key AND val (k01,v01,k23,v23 pattern).
__global__ __launch_bounds__(256) void pack_qv_kernel(
    const float* __restrict__ q, const float* __restrict__ v,
    unsigned int* __restrict__ qvT) {
  __shared__ float tq[TT][TT + 1];
  __shared__ float tv[TT][TT + 1];
  const int b = blockIdx.z;
  const float* qb = q + (size_t)b * CHAN * NPTS;
  const float* vb = v + (size_t)b * CHAN * NPTS;
  unsigned int* out = qvT + (size_t)b * NPTS * ROWU;
  const int n0 = blockIdx.x * TT;
  const int c0 = blockIdx.y * TT;
  const int t = threadIdx.x;

  {  // load both tiles: float4 along n (coalesced)
    const int cl = t >> 3, nq = (t & 7) * 4;
    const int c = c0 + cl;
    if (c < CHAN) {
      const float4 a = *(const float4*)&qb[(size_t)c * NPTS + n0 + nq];
      tq[cl][nq + 0] = a.x; tq[cl][nq + 1] = a.y;
      tq[cl][nq + 2] = a.z; tq[cl][nq + 3] = a.w;
      const float4 w = *(const float4*)&vb[(size_t)c * NPTS + n0 + nq];
      tv[cl][nq + 0] = w.x; tv[cl][nq + 1] = w.y;
      tv[cl][nq + 2] = w.z; tv[cl][nq + 3] = w.w;
    }
  }
  __syncthreads();
  {  // store packed dim-pairs: uint4 along c (coalesced 128B per 8-thr cluster)
    const int nl = t >> 3, cq = (t & 7) * 4;
    const int c = c0 + cq;   // multiple of 4
    if (c < CHAN) {
      const int g = c >> 4, r = c & 15;   // r in {0,4,8,12}
      __half2 k01 = __halves2half2(__float2half_rn(tq[cq + 0][nl]),
                                   __float2half_rn(tq[cq + 1][nl]));
      __half2 v01 = __halves2half2(__float2half_rn(tv[cq + 0][nl]),
                                   __float2half_rn(tv[cq + 1][nl]));
      __half2 k23 = __halves2half2(__float2half_rn(tq[cq + 2][nl]),
                                   __float2half_rn(tq[cq + 3][nl]));
      __half2 v23 = __halves2half2(__float2half_rn(tv[cq + 2][nl]),
                                   __float2half_rn(tv[cq + 3][nl]));
      *(uint4*)&out[(size_t)(n0 + nl) * ROWU + g * 16 + r] =
          make_uint4(*(unsigned int*)&k01, *(unsigned int*)&v01,
                     *(unsigned int*)&k23, *(unsigned int*)&v23);
    }
  }
}

// R5 quad-per-point: wave = 16 points x 4 dim-quad lanes; ONE uint4 gather
// per (point,neighbor); DPP quad ops for id-bcast + dot butterfly; no-max
// softmax with fused value accumulation.
// R6 residency + flush redesign: PCHUNK 32 -> 64 resident block-slots per
// XCD cover EXACTLY 2 pairs = 2MB of gather slices (was 3.05MB vs 4MB L2
// at ~75% capacity -> conflict misses: FETCH 210MB, ~27% gather miss at
// ~900cy; per-CU in-flight capacity saturated => delivered rate = cap/lat,
// so latency is the only lever). part[] and the reduce kernel are deleted:
// lcent flushes straight to cent via coalesced global atomicAdd (slice is
// XCD-local-L2-hot; ~19M lane-RMWs), cent zeroed by hipMemsetAsync.
__global__ __launch_bounds__(512, 4) void gtl_kernel(
    const unsigned int* __restrict__ qvT,  // (B, N, ROWU) packed
    const int*   __restrict__ idx,         // (B, N, K)
    float* __restrict__ feat,              // (B, C, N)
    float* __restrict__ cent)              // (NPAIR, NPTS) pre-zeroed
{
  // ---- XCD-partitioned decode: grid 1152 = 8*144, no dummies ----
  const int i = blockIdx.x;
  const int x = i & 7, sblk = i >> 3;     // sblk in 0..143
  int pair, chunk;
  if (sblk < 128) { pair = x + 8 * (sblk >> 5); chunk = sblk & 31; }
  else            { pair = 32 + (x >> 1); chunk = (sblk - 128) + 16 * (x & 1); }
  const int b = pair / GRP;
  const int g = pair - b * GRP;

  __shared__ float lcent[NPTS];     // 64 KB private cent[b,g,:]
  const int tid = threadIdx.x;

  f4v* l4 = (f4v*)lcent;
  #pragma unroll
  for (int ii = 0; ii < NPTS / 4 / 512; ++ii)
    l4[ii * 512 + tid] = (f4v){0.f, 0.f, 0.f, 0.f};
  __syncthreads();

  // chunk -> 4 groups of 128 points (128 groups per pair, 32 chunks x 4)
  const int NG = 4;
  const int gstart = 4 * chunk;

  const int lane = tid & 63;
  const int wv   = tid >> 6;        // 8 waves / block
  const int slot = lane >> 2;       // point within wave [0,16)
  const int d    = lane & 3;        // dim-quad within group [0,4)

  // Uniform (SGPR) byte bases; per-lane 32-bit offsets (qvT slice < 9.4 MB).
  const char* qvb  = (const char*)qvT + (size_t)b * NPTS * (ROWU * 4);
  const char* idxB = (const char*)idx + (size_t)b * NPTS * (KNN * 4);
  const unsigned laneB  = (unsigned)(g * 64 + d * 16);   // g*DIM*4 + 4*d*4
  const unsigned idxoff = (unsigned)(d * 16);

  // ---- prologue: iteration 0's idx quad + q fragment ----
  int n = gstart * 128 + wv * 16 + slot;
  i4v idq = __builtin_nontemporal_load(
      (const i4v*)(idxB + (unsigned)n * 64u + idxoff));   // ids 4d..4d+3
  uint4 qq = *(const uint4*)(qvb + (unsigned)n * (ROWU * 4u) + laneB);

  for (int it = 0; it < NG; ++it) {
    const h2v q01 = as_h2(qq.x);
    const h2v q23 = as_h2(qq.z);

    // ---- burst: 16 uint4 gathers = 16 points x 16 neighbors in flight ----
    // Neighbor K's id lives in quad-lane (K>>2), component (K&3): DPP bcast.
    uint4 kvp[KNN];
#define GSTEP(K)                                                             \
    {                                                                        \
      const int mk = ibcast<((K) >> 2)>(                                     \
          ((K) & 3) == 0 ? idq.x : ((K) & 3) == 1 ? idq.y                    \
                         : ((K) & 3) == 2 ? idq.z : idq.w);                  \
      kvp[K] = *(const uint4*)(qvb + (unsigned)mk * (ROWU * 4u) + laneB);    \
    }
    GSTEP(0)  GSTEP(1)  GSTEP(2)  GSTEP(3)
    GSTEP(4)  GSTEP(5)  GSTEP(6)  GSTEP(7)
    GSTEP(8)  GSTEP(9)  GSTEP(10) GSTEP(11)
    GSTEP(12) GSTEP(13) GSTEP(14) GSTEP(15)
#undef GSTEP

    // ---- prefetch next iteration's idx quad + q fragment under the flight ----
    const int itn = (it + 1 < NG) ? it + 1 : it;   // clamp: no OOB
    const int nn = (gstart + itn) * 128 + wv * 16 + slot;
    const i4v idqn = __builtin_nontemporal_load(
        (const i4v*)(idxB + (unsigned)nn * 64u + idxoff));
    const uint4 qqn = *(const uint4*)(qvb + (unsigned)nn * (ROWU * 4u) + laneB);

    // Pin: everything above issues before anything below schedules.
    __builtin_amdgcn_sched_barrier(0);

    // ---- consume in arrival order: score (fdot2 + 2-level DPP butterfly),
    //      no-max exp, fused value accumulation. kvp[K] dies per step. ----
    float p[KNN];
    float sum = 0.f, a0 = 0.f, a1 = 0.f, a2 = 0.f, a3 = 0.f;
#define CSTEP(K)                                                             \
    {                                                                        \
      float s = __builtin_amdgcn_fdot2(as_h2(kvp[K].x), q01, 0.f, false);    \
      s = __builtin_amdgcn_fdot2(as_h2(kvp[K].z), q23, s, false);            \
      s += fxor<0xB1>(s);                                                    \
      s += fxor<0x4E>(s);                                                    \
      const float e = __expf(s);                                             \
      p[K] = e; sum += e;                                                    \
      const float2 v01 = __half22float2(*(const __half2*)&kvp[K].y);         \
      const float2 v23 = __half22float2(*(const __half2*)&kvp[K].w);         \
      a0 += e * v01.x; a1 += e * v01.y; a2 += e * v23.x; a3 += e * v23.y;    \
    }
    CSTEP(0)  CSTEP(1)  CSTEP(2)  CSTEP(3)
    CSTEP(4)  CSTEP(5)  CSTEP(6)  CSTEP(7)
    CSTEP(8)  CSTEP(9)  CSTEP(10) CSTEP(11)
    CSTEP(12) CSTEP(13) CSTEP(14) CSTEP(15)
#undef CSTEP

    const float inv = 1.f / sum;

    // centrality: lane d scatters neighbors k=4d..4d+3 (ids = idq.x..w).
    // p[] indices are compile-time; select over runtime d via cndmask.
    const float w0 = (d == 0 ? p[0] : d == 1 ? p[4] : d == 2 ? p[8]  : p[12]) * inv;
    const float w1 = (d == 0 ? p[1] : d == 1 ? p[5] : d == 2 ? p[9]  : p[13]) * inv;
    const float w2 = (d == 0 ? p[2] : d == 1 ? p[6] : d == 2 ? p[10] : p[14]) * inv;
    const float w3 = (d == 0 ? p[3] : d == 1 ? p[7] : d == 2 ? p[11] : p[15]) * inv;
    atomicAdd(&lcent[idq.x], w0);
    atomicAdd(&lcent[idq.y], w1);
    atomicAdd(&lcent[idq.z], w2);
    atomicAdd(&lcent[idq.w], w3);

    // feat write: dims 4d..4d+3 of point n; nt: don't pollute the L2 slice
    float* fb = feat + ((size_t)b * CHAN + g * DIM + 4 * d) * NPTS + n;
    __builtin_nontemporal_store(a0 * inv, fb);
    __builtin_nontemporal_store(a1 * inv, fb + NPTS);
    __builtin_nontemporal_store(a2 * inv, fb + 2 * NPTS);
    __builtin_nontemporal_store(a3 * inv, fb + 3 * NPTS);

    // rotate prefetched state
    n = nn; idq = idqn; qq = qqn;
  }

  __syncthreads();
  // flush private slice straight into cent (coalesced global atomics;
  // the pair's 64KB cent slice stays hot in this XCD's L2 across all
  // 32 chunk-blocks; replaces part[] + reduce kernel entirely)
  float* cb = cent + (size_t)pair * NPTS;
  #pragma unroll
  for (int ii = 0; ii < NPTS / 512; ++ii)
    atomicAdd(&cb[ii * 512 + tid], lcent[ii * 512 + tid]);
}

extern "C" void kernel_launch(void* const* d_in, const int* in_sizes, int n_in,
                              void* d_out, int out_size, void* d_ws, size_t ws_size,
                              hipStream_t stream) {
  const float* q   = (const float*)d_in[0];   // queryandkey (B,C,N)
  const float* v   = (const float*)d_in[1];   // value (B,C,N)
  const int*   idx = (const int*)d_in[2];     // idx_knn (B,N,K)

  float* feat = (float*)d_out;                       // (B,C,N)
  float* cent = feat + (size_t)BATCH * CHAN * NPTS;  // (B,G,N)

  unsigned int* qvT = (unsigned int*)d_ws;           // (B,N,ROWU) packed

  // 0) zero cent (stream-ordered; gtl accumulates into it atomically)
  hipMemsetAsync(cent, 0, (size_t)NPAIR * NPTS * sizeof(float), stream);

  // 1) pack q,v into dim-pair interleaved fp16 rows
  dim3 tg(NPTS / TT, (CHAN + TT - 1) / TT, BATCH);
  pack_qv_kernel<<<tg, 256, 0, stream>>>(q, v, qvT);

  // 2) main fused kernel: 1152 blocks x 512 threads, 64KB LDS, XCD swizzle;
  //    exactly 2 resident pairs per XCD -> 2MB gather slices fit 4MB L2
  gtl_kernel<<<NPAIR * PCHUNK, 512, 0, stream>>>(qvT, idx, feat, cent);
}

// Round 7
// 233.165 us; speedup vs baseline: 1.0048x; 1.0048x over previous
//
#include <hip/hip_runtime.h>
#include <hip/hip_fp16.h>

// Problem constants (fixed by setup_inputs / GTLModuleV1)
#define BATCH 4
#define CHAN  144
#define NPTS  16384
#define KNN   16
#define GRP   9
#define DIM   16
#define ROWU  (GRP * DIM)        // 144 uint32 per point = 576 B row
#define PCHUNK 32                // chunks per (b,g) pair -> 36*32 = 1152 blocks
#define NPAIR (BATCH * GRP)      // 36

#define TT 32

typedef __attribute__((ext_vector_type(2))) _Float16 h2v;
typedef __attribute__((ext_vector_type(4))) float f4v;   // clang vector: nt ops OK
typedef __attribute__((ext_vector_type(4))) int   i4v;   // clang vector: nt ops OK
__device__ __forceinline__ h2v as_h2(unsigned int u) {
  union { unsigned int u; h2v h; } c; c.u = u; return c.h;
}

// DPP helpers: quad_perm ops are VALU (no LDS pipe, ~4cy vs ~40cy bpermute).
template<int J>  // broadcast quad-lane J to all 4 lanes of the quad
__device__ __forceinline__ int ibcast(int v) {
  return __builtin_amdgcn_update_dpp(0, v, (J) * 0x55, 0xF, 0xF, true);
}
template<int C>  // C=0xB1: xor1 swap; C=0x4E: xor2 swap (within quad)
__device__ __forceinline__ float fxor(float x) {
  int r = __builtin_amdgcn_update_dpp(0, __builtin_bit_cast(int, x), C, 0xF, 0xF, true);
  return __builtin_bit_cast(float, r);
}

// (C,N) fp32 q,v -> (N, 144 uints): per group g, uint 2i = h2(k_{2i},k_{2i+1}),
// uint 2i+1 = h2(v_{2i},v_{2i+1}). Each (g,m) slice = 64 B; a uint4 at uint
// offset 16g+4d = dims 4d..4d+3 of key AND val (k01,v01,k23,v23 pattern).
__global__ __launch_bounds__(256) void pack_qv_kernel(
    const float* __restrict__ q, const float* __restrict__ v,
    unsigned int* __restrict__ qvT) {
  __shared__ float tq[TT][TT + 1];
  __shared__ float tv[TT][TT + 1];
  const int b = blockIdx.z;
  const float* qb = q + (size_t)b * CHAN * NPTS;
  const float* vb = v + (size_t)b * CHAN * NPTS;
  unsigned int* out = qvT + (size_t)b * NPTS * ROWU;
  const int n0 = blockIdx.x * TT;
  const int c0 = blockIdx.y * TT;
  const int t = threadIdx.x;

  {  // load both tiles: float4 along n (coalesced)
    const int cl = t >> 3, nq = (t & 7) * 4;
    const int c = c0 + cl;
    if (c < CHAN) {
      const float4 a = *(const float4*)&qb[(size_t)c * NPTS + n0 + nq];
      tq[cl][nq + 0] = a.x; tq[cl][nq + 1] = a.y;
      tq[cl][nq + 2] = a.z; tq[cl][nq + 3] = a.w;
      const float4 w = *(const float4*)&vb[(size_t)c * NPTS + n0 + nq];
      tv[cl][nq + 0] = w.x; tv[cl][nq + 1] = w.y;
      tv[cl][nq + 2] = w.z; tv[cl][nq + 3] = w.w;
    }
  }
  __syncthreads();
  {  // store packed dim-pairs: uint4 along c (coalesced 128B per 8-thr cluster)
    const int nl = t >> 3, cq = (t & 7) * 4;
    const int c = c0 + cq;   // multiple of 4
    if (c < CHAN) {
      const int g = c >> 4, r = c & 15;   // r in {0,4,8,12}
      __half2 k01 = __halves2half2(__float2half_rn(tq[cq + 0][nl]),
                                   __float2half_rn(tq[cq + 1][nl]));
      __half2 v01 = __halves2half2(__float2half_rn(tv[cq + 0][nl]),
                                   __float2half_rn(tv[cq + 1][nl]));
      __half2 k23 = __halves2half2(__float2half_rn(tq[cq + 2][nl]),
                                   __float2half_rn(tq[cq + 3][nl]));
      __half2 v23 = __halves2half2(__float2half_rn(tv[cq + 2][nl]),
                                   __float2half_rn(tv[cq + 3][nl]));
      *(uint4*)&out[(size_t)(n0 + nl) * ROWU + g * 16 + r] =
          make_uint4(*(unsigned int*)&k01, *(unsigned int*)&v01,
                     *(unsigned int*)&k23, *(unsigned int*)&v23);
    }
  }
}

// R5 quad-per-point: wave = 16 points x 4 dim-quad lanes; ONE uint4 gather
// per (point,neighbor); DPP quad ops for id-bcast + dot butterfly; no-max
// softmax with fused value accumulation.
// R6: PCHUNK 32 -> exactly 2 resident pairs (2MB gather slices) per XCD L2;
// FETCH collapsed 210->94MB (gather misses gone) but the cent atomic flush
// regressed time: all 32 chunk-blocks of a pair swept the same 64KB slice
// from offset 0 -> per-line atomic queues 32 deep at every block boundary.
// R7 flush fix: (a) rotate each block's flush start by chunk*2KB so blocks
// of a pair hit disjoint regions at any instant (same-line concurrency
// 32 -> ~1); (b) skip zero entries (block scatters 8192 weights into 16384
// bins -> >=54% of lcent is exactly 0; exec-masked atomics halve lane-RMWs).
__global__ __launch_bounds__(512, 4) void gtl_kernel(
    const unsigned int* __restrict__ qvT,  // (B, N, ROWU) packed
    const int*   __restrict__ idx,         // (B, N, K)
    float* __restrict__ feat,              // (B, C, N)
    float* __restrict__ cent)              // (NPAIR, NPTS) pre-zeroed
{
  // ---- XCD-partitioned decode: grid 1152 = 8*144, no dummies ----
  const int i = blockIdx.x;
  const int x = i & 7, sblk = i >> 3;     // sblk in 0..143
  int pair, chunk;
  if (sblk < 128) { pair = x + 8 * (sblk >> 5); chunk = sblk & 31; }
  else            { pair = 32 + (x >> 1); chunk = (sblk - 128) + 16 * (x & 1); }
  const int b = pair / GRP;
  const int g = pair - b * GRP;

  __shared__ float lcent[NPTS];     // 64 KB private cent[b,g,:]
  const int tid = threadIdx.x;

  f4v* l4 = (f4v*)lcent;
  #pragma unroll
  for (int ii = 0; ii < NPTS / 4 / 512; ++ii)
    l4[ii * 512 + tid] = (f4v){0.f, 0.f, 0.f, 0.f};
  __syncthreads();

  // chunk -> 4 groups of 128 points (128 groups per pair, 32 chunks x 4)
  const int NG = 4;
  const int gstart = 4 * chunk;

  const int lane = tid & 63;
  const int wv   = tid >> 6;        // 8 waves / block
  const int slot = lane >> 2;       // point within wave [0,16)
  const int d    = lane & 3;        // dim-quad within group [0,4)

  // Uniform (SGPR) byte bases; per-lane 32-bit offsets (qvT slice < 9.4 MB).
  const char* qvb  = (const char*)qvT + (size_t)b * NPTS * (ROWU * 4);
  const char* idxB = (const char*)idx + (size_t)b * NPTS * (KNN * 4);
  const unsigned laneB  = (unsigned)(g * 64 + d * 16);   // g*DIM*4 + 4*d*4
  const unsigned idxoff = (unsigned)(d * 16);

  // ---- prologue: iteration 0's idx quad + q fragment ----
  int n = gstart * 128 + wv * 16 + slot;
  i4v idq = __builtin_nontemporal_load(
      (const i4v*)(idxB + (unsigned)n * 64u + idxoff));   // ids 4d..4d+3
  uint4 qq = *(const uint4*)(qvb + (unsigned)n * (ROWU * 4u) + laneB);

  for (int it = 0; it < NG; ++it) {
    const h2v q01 = as_h2(qq.x);
    const h2v q23 = as_h2(qq.z);

    // ---- burst: 16 uint4 gathers = 16 points x 16 neighbors in flight ----
    // Neighbor K's id lives in quad-lane (K>>2), component (K&3): DPP bcast.
    uint4 kvp[KNN];
#define GSTEP(K)                                                             \
    {                                                                        \
      const int mk = ibcast<((K) >> 2)>(                                     \
          ((K) & 3) == 0 ? idq.x : ((K) & 3) == 1 ? idq.y                    \
                         : ((K) & 3) == 2 ? idq.z : idq.w);                  \
      kvp[K] = *(const uint4*)(qvb + (unsigned)mk * (ROWU * 4u) + laneB);    \
    }
    GSTEP(0)  GSTEP(1)  GSTEP(2)  GSTEP(3)
    GSTEP(4)  GSTEP(5)  GSTEP(6)  GSTEP(7)
    GSTEP(8)  GSTEP(9)  GSTEP(10) GSTEP(11)
    GSTEP(12) GSTEP(13) GSTEP(14) GSTEP(15)
#undef GSTEP

    // ---- prefetch next iteration's idx quad + q fragment under the flight ----
    const int itn = (it + 1 < NG) ? it + 1 : it;   // clamp: no OOB
    const int nn = (gstart + itn) * 128 + wv * 16 + slot;
    const i4v idqn = __builtin_nontemporal_load(
        (const i4v*)(idxB + (unsigned)nn * 64u + idxoff));
    const uint4 qqn = *(const uint4*)(qvb + (unsigned)nn * (ROWU * 4u) + laneB);

    // Pin: everything above issues before anything below schedules.
    __builtin_amdgcn_sched_barrier(0);

    // ---- consume in arrival order: score (fdot2 + 2-level DPP butterfly),
    //      no-max exp, fused value accumulation. kvp[K] dies per step. ----
    float p[KNN];
    float sum = 0.f, a0 = 0.f, a1 = 0.f, a2 = 0.f, a3 = 0.f;
#define CSTEP(K)                                                             \
    {                                                                        \
      float s = __builtin_amdgcn_fdot2(as_h2(kvp[K].x), q01, 0.f, false);    \
      s = __builtin_amdgcn_fdot2(as_h2(kvp[K].z), q23, s, false);            \
      s += fxor<0xB1>(s);                                                    \
      s += fxor<0x4E>(s);                                                    \
      const float e = __expf(s);                                             \
      p[K] = e; sum += e;                                                    \
      const float2 v01 = __half22float2(*(const __half2*)&kvp[K].y);         \
      const float2 v23 = __half22float2(*(const __half2*)&kvp[K].w);         \
      a0 += e * v01.x; a1 += e * v01.y; a2 += e * v23.x; a3 += e * v23.y;    \
    }
    CSTEP(0)  CSTEP(1)  CSTEP(2)  CSTEP(3)
    CSTEP(4)  CSTEP(5)  CSTEP(6)  CSTEP(7)
    CSTEP(8)  CSTEP(9)  CSTEP(10) CSTEP(11)
    CSTEP(12) CSTEP(13) CSTEP(14) CSTEP(15)
#undef CSTEP

    const float inv = 1.f / sum;

    // centrality: lane d scatters neighbors k=4d..4d+3 (ids = idq.x..w).
    // p[] indices are compile-time; select over runtime d via cndmask.
    const float w0 = (d == 0 ? p[0] : d == 1 ? p[4] : d == 2 ? p[8]  : p[12]) * inv;
    const float w1 = (d == 0 ? p[1] : d == 1 ? p[5] : d == 2 ? p[9]  : p[13]) * inv;
    const float w2 = (d == 0 ? p[2] : d == 1 ? p[6] : d == 2 ? p[10] : p[14]) * inv;
    const float w3 = (d == 0 ? p[3] : d == 1 ? p[7] : d == 2 ? p[11] : p[15]) * inv;
    atomicAdd(&lcent[idq.x], w0);
    atomicAdd(&lcent[idq.y], w1);
    atomicAdd(&lcent[idq.z], w2);
    atomicAdd(&lcent[idq.w], w3);

    // feat write: dims 4d..4d+3 of point n; nt: don't pollute the L2 slice
    float* fb = feat + ((size_t)b * CHAN + g * DIM + 4 * d) * NPTS + n;
    __builtin_nontemporal_store(a0 * inv, fb);
    __builtin_nontemporal_store(a1 * inv, fb + NPTS);
    __builtin_nontemporal_store(a2 * inv, fb + 2 * NPTS);
    __builtin_nontemporal_store(a3 * inv, fb + 3 * NPTS);

    // rotate prefetched state
    n = nn; idq = idqn; qq = qqn;
  }

  __syncthreads();
  // flush private slice into cent. Rotation: block with chunk c starts at
  // float offset c*512, so the pair's 32 blocks sweep disjoint 2KB regions
  // at any instant (kills same-line atomic queueing). Zero-skip: >=54% of
  // entries are exactly 0 (8192 weights scattered into 16384 bins).
  float* cb = cent + (size_t)pair * NPTS;
  #pragma unroll
  for (int ii = 0; ii < NPTS / 512; ++ii) {
    const int ofs = (((ii + chunk) & 31) << 9) + tid;
    const float val = lcent[ofs];
    if (val != 0.f) atomicAdd(&cb[ofs], val);
  }
}

extern "C" void kernel_launch(void* const* d_in, const int* in_sizes, int n_in,
                              void* d_out, int out_size, void* d_ws, size_t ws_size,
                              hipStream_t stream) {
  const float* q   = (const float*)d_in[0];   // queryandkey (B,C,N)
  const float* v   = (const float*)d_in[1];   // value (B,C,N)
  const int*   idx = (const int*)d_in[2];     // idx_knn (B,N,K)

  float* feat = (float*)d_out;                       // (B,C,N)
  float* cent = feat + (size_t)BATCH * CHAN * NPTS;  // (B,G,N)

  unsigned int* qvT = (unsigned int*)d_ws;           // (B,N,ROWU) packed

  // 0) zero cent (stream-ordered; gtl accumulates into it atomically)
  hipMemsetAsync(cent, 0, (size_t)NPAIR * NPTS * sizeof(float), stream);

  // 1) pack q,v into dim-pair interleaved fp16 rows
  dim3 tg(NPTS / TT, (CHAN + TT - 1) / TT, BATCH);
  pack_qv_kernel<<<tg, 256, 0, stream>>>(q, v, qvT);

  // 2) main fused kernel: 1152 blocks x 512 threads, 64KB LDS, XCD swizzle;
  //    exactly 2 resident pairs per XCD -> 2MB gather slices fit 4MB L2
  gtl_kernel<<<NPAIR * PCHUNK, 512, 0, stream>>>(qvT, idx, feat, cent);
}